// Round 7
// baseline (35.717 us; speedup 1.0000x reference)
//
#include <hip/hip_runtime.h>
#include <hip/hip_bf16.h>
#include <cmath>

#define BB 256
#define TT 2048
#define ATTN_RNN 1024
#define HIDDEN 128
#define DYN_CH 8
#define DYN_K 21
#define PRIOR_LEN 11
#define KSCALE 2.8853900817779268f   /* 2*log2(e) */

typedef __attribute__((ext_vector_type(8))) short  short8v;   // 8 bf16
typedef __attribute__((ext_vector_type(4))) float  float4v;

struct PriorArg { float v[PRIOR_LEN]; };

__device__ __forceinline__ float fast_tanh(float x) {
    float e = __expf(2.0f * x);
    return 1.0f - 2.0f * __builtin_amdgcn_rcpf(e + 1.0f);
}

__device__ __forceinline__ unsigned pk_bf16(float lo, float hi) {
    union { __hip_bfloat162 h; unsigned u; } u;
    u.h = __float22bfloat162_rn(make_float2(lo, hi));   // v_cvt_pk_bf16_f32
    return u.u;
}

__device__ __forceinline__ void setpk(short8v& d, int i, float lo, float hi) {
    union { __hip_bfloat162 h; short s[2]; } u;
    u.h = __float22bfloat162_rn(make_float2(lo, hi));
    d[i] = u.s[0]; d[i + 1] = u.s[1];
}

__global__ __launch_bounds__(1024, 4) void dca_kernel(
    const float* __restrict__ s,  const float* __restrict__ alpha,
    const float* __restrict__ Ww, const float* __restrict__ Wb,
    const float* __restrict__ Vw, const float* __restrict__ Fw,
    const float* __restrict__ Uw, const float* __restrict__ Tw,
    const float* __restrict__ Tb, const float* __restrict__ vw,
    float* __restrict__ out, PriorArg pf)
{
    const int b    = blockIdx.x;
    const int tid  = threadIdx.x;
    const int lane = tid & 63;
    const int wid  = tid >> 6;          // 0..15
    const int row  = lane & 15;
    const int kb   = lane >> 4;         // 0..3 (k-block of 8)

    __shared__ __align__(16) float h_sh[HIDDEN];
    __shared__ float G_sh[DYN_CH * DYN_K];
    // Wpk[j][kp]: bf16 pair (k=2kp, 2kp+1), KSCALE folded; kp=10 hi = KSCALE*Tb; kp=11 = 0
    __shared__ __align__(16) unsigned Wpk[HIDDEN * 12];
    __shared__ float vv_sh[HIDDEN];
    __shared__ __align__(16) float a_sh[TT + 48];   // a_sh[i] = alpha[b, i-10], 0-padded
    __shared__ __align__(16) float e_sh[TT];
    __shared__ float red_max[16], red_sum[16];
    __shared__ float sumv_sh;

    // ---- independent staging (no barrier needed before phase 1) ----
    for (int i = tid; i < TT + 48; i += 1024)
        a_sh[i] = (i >= 10 && i < TT + 10) ? alpha[b * TT + (i - 10)] : 0.0f;
    if (tid < HIDDEN) vv_sh[tid] = vw[tid];
    if (tid < 64) {
        float sv = vw[tid] + vw[tid + 64];
        #pragma unroll
        for (int o = 32; o > 0; o >>= 1) sv += __shfl_xor(sv, o);
        if (tid == 0) sumv_sh = sv;
    }

    // ---- phase 1: h = tanh(s @ Ww^T + Wb); s read straight from global ----
    // wave w owns j = w*8..w*8+7; lane = (r: row-in-quad, l: k-chunk of 4 floats)
    {
        const int r = lane >> 4;
        const int l = lane & 15;
        const float4* sg = (const float4*)(s + b * ATTN_RNN) + l;   // sg[c*16]
        #pragma unroll
        for (int jg = 0; jg < 2; ++jg) {
            const int j = wid * 8 + jg * 4 + r;
            const float4* wrow = (const float4*)(Ww + j * ATTN_RNN) + l;
            float4 wbuf[8], sbuf[8];
            float acc = 0.f;
            #pragma unroll
            for (int c = 0; c < 8; ++c) wbuf[c] = wrow[c * 16];
            #pragma unroll
            for (int c = 0; c < 8; ++c) sbuf[c] = sg[c * 16];
            #pragma unroll
            for (int c = 0; c < 8; ++c) {
                acc = fmaf(wbuf[c].x, sbuf[c].x, acc);
                acc = fmaf(wbuf[c].y, sbuf[c].y, acc);
                acc = fmaf(wbuf[c].z, sbuf[c].z, acc);
                acc = fmaf(wbuf[c].w, sbuf[c].w, acc);
            }
            #pragma unroll
            for (int c = 0; c < 8; ++c) wbuf[c] = wrow[(c + 8) * 16];
            #pragma unroll
            for (int c = 0; c < 8; ++c) sbuf[c] = sg[(c + 8) * 16];
            #pragma unroll
            for (int c = 0; c < 8; ++c) {
                acc = fmaf(wbuf[c].x, sbuf[c].x, acc);
                acc = fmaf(wbuf[c].y, sbuf[c].y, acc);
                acc = fmaf(wbuf[c].z, sbuf[c].z, acc);
                acc = fmaf(wbuf[c].w, sbuf[c].w, acc);
            }
            acc += __shfl_xor(acc, 1);
            acc += __shfl_xor(acc, 2);
            acc += __shfl_xor(acc, 4);
            acc += __shfl_xor(acc, 8);
            if (l == 0) h_sh[j] = fast_tanh(acc + Wb[j]);
        }
    }
    __syncthreads();

    // ---- phase 2: G = h @ Vw^T, 4-way split-K over 672 threads ----
    if (tid < DYN_CH * DYN_K * 4) {
        const int g = tid >> 2, part = tid & 3;
        const float4* vr = (const float4*)(Vw + g * HIDDEN + part * 32);
        const float4* hh = (const float4*)(h_sh + part * 32);
        float acc = 0.f;
        #pragma unroll
        for (int c = 0; c < 8; ++c) {
            float4 v4 = vr[c]; float4 h4 = hh[c];
            acc = fmaf(v4.x, h4.x, acc); acc = fmaf(v4.y, h4.y, acc);
            acc = fmaf(v4.z, h4.z, acc); acc = fmaf(v4.w, h4.w, acc);
        }
        acc += __shfl_xor(acc, 1);
        acc += __shfl_xor(acc, 2);
        if (part == 0) G_sh[g] = acc;
    }
    __syncthreads();

    // ---- phase 3: bf16-pair-packed Weff (KSCALE folded, Tb in k=21 slot) ----
    for (int idx = tid; idx < HIDDEN * 12; idx += 1024) {
        const int j = idx / 12, kp = idx - j * 12;
        float v0 = 0.f, v1 = 0.f;
        if (kp < 11) {
            const int k0 = 2 * kp;
            float a0 = 0.f, a1 = 0.f;
            #pragma unroll
            for (int c = 0; c < 8; ++c) {
                const float u = Uw[j * 8 + c], t = Tw[j * 8 + c];
                a0 = fmaf(u, Fw[c * 21 + k0], a0);
                a0 = fmaf(t, G_sh[c * 21 + k0], a0);
                if (kp < 10) {
                    a1 = fmaf(u, Fw[c * 21 + k0 + 1], a1);
                    a1 = fmaf(t, G_sh[c * 21 + k0 + 1], a1);
                }
            }
            v0 = KSCALE * a0;
            v1 = (kp < 10) ? KSCALE * a1 : KSCALE * Tb[j];
        }
        Wpk[idx] = pk_bf16(v0, v1);
    }
    __syncthreads();

    // ---- phase 4: A = Weff (j rows), B = sliding alpha window (t cols) ----
    short8v wfrag[8];
    float4v vvr[8];
    #pragma unroll
    for (int n = 0; n < 8; ++n) {
        const int j = n * 16 + row;
        wfrag[n] = (kb < 3) ? *(const short8v*)&Wpk[j * 12 + kb * 4]
                            : (short8v){0, 0, 0, 0, 0, 0, 0, 0};
        vvr[n] = *(const float4v*)&vv_sh[n * 16 + kb * 4];
    }

    for (int i = 0; i < 8; ++i) {
        const int t0 = (wid * 8 + i) * 16;
        const float* ab = &a_sh[t0 + row + kb * 8];     // in-bounds for all kb
        float a0 = ab[0], a1 = ab[1], a2 = ab[2], a3 = ab[3];
        float a4 = ab[4], a5 = ab[5], a6 = ab[6], a7 = ab[7];
        short8v af;
        setpk(af, 0, a0, a1); setpk(af, 2, a2, a3);
        setpk(af, 4, a4, a5); setpk(af, 6, a6, a7);
        if (kb >= 2) { setpk(af, 4, a4, 1.0f); setpk(af, 6, 0.f, 0.f); }  // k=21 -> Tb slot
        if (kb == 3) { setpk(af, 0, 0.f, 0.f); setpk(af, 2, 0.f, 0.f);
                       setpk(af, 4, 0.f, 0.f); }

        float4v accs[8];
        #pragma unroll
        for (int n = 0; n < 8; ++n) {
            float4v z = {0.f, 0.f, 0.f, 0.f};
            accs[n] = __builtin_amdgcn_mfma_f32_16x16x32_bf16(wfrag[n], af, z, 0, 0, 0);
        }

        float ep0 = 0.f, ep1 = 0.f;
        #pragma unroll
        for (int n = 0; n < 8; n += 2) {
            #pragma unroll
            for (int r = 0; r < 4; ++r) {
                float sg0 = __builtin_amdgcn_rcpf(__builtin_amdgcn_exp2f(accs[n][r]) + 1.0f);
                float sg1 = __builtin_amdgcn_rcpf(__builtin_amdgcn_exp2f(accs[n + 1][r]) + 1.0f);
                ep0 = fmaf(vvr[n][r], sg0, ep0);
                ep1 = fmaf(vvr[n + 1][r], sg1, ep1);
            }
        }
        float ep = ep0 + ep1;
        ep += __shfl_xor(ep, 16);
        ep += __shfl_xor(ep, 32);
        if (lane < 16) e_sh[t0 + lane] = ep;
    }
    __syncthreads();

    // ---- final: prior + softmax, 2 positions per thread ----
    const float sumv = sumv_sh;
    const int tp = tid * 2;
    float tot0 = e_sh[tp], tot1 = e_sh[tp + 1];
    float pr0 = 0.f, pr1 = 0.f;
    #pragma unroll
    for (int k = 0; k < PRIOR_LEN; ++k) {
        pr0 = fmaf(a_sh[tp + k],     pf.v[k], pr0);
        pr1 = fmaf(a_sh[tp + 1 + k], pf.v[k], pr1);
    }
    float e0 = sumv - 2.f * tot0 + __logf(fmaxf(pr0, 1e-6f));
    float e1 = sumv - 2.f * tot1 + __logf(fmaxf(pr1, 1e-6f));

    float m = fmaxf(e0, e1);
    #pragma unroll
    for (int o = 32; o > 0; o >>= 1) m = fmaxf(m, __shfl_xor(m, o));
    if (lane == 0) red_max[wid] = m;
    __syncthreads();
    float gm = red_max[0];
    #pragma unroll
    for (int w = 1; w < 16; ++w) gm = fmaxf(gm, red_max[w]);

    float x0 = __expf(e0 - gm), x1 = __expf(e1 - gm);
    float sloc = x0 + x1;
    #pragma unroll
    for (int o = 32; o > 0; o >>= 1) sloc += __shfl_xor(sloc, o);
    if (lane == 0) red_sum[wid] = sloc;
    __syncthreads();
    float gs = 0.f;
    #pragma unroll
    for (int w = 0; w < 16; ++w) gs += red_sum[w];
    float inv = 1.0f / gs;

    ((float2*)(out + b * TT))[tid] = make_float2(x0 * inv, x1 * inv);
}

extern "C" void kernel_launch(void* const* d_in, const int* in_sizes, int n_in,
                              void* d_out, int out_size, void* d_ws, size_t ws_size,
                              hipStream_t stream) {
    (void)in_sizes; (void)n_in; (void)d_ws; (void)ws_size; (void)out_size;

    PriorArg pf;
    const double a = 0.1, bpr = 0.9;
    const int n = PRIOR_LEN - 1;
    const double norm = lgamma(a) + lgamma(bpr) - lgamma(a + bpr);
    for (int k = 0; k <= n; ++k) {
        double lp = lgamma((double)n + 1.0) - lgamma((double)k + 1.0)
                  - lgamma((double)(n - k) + 1.0)
                  + lgamma((double)k + a) + lgamma((double)(n - k) + bpr)
                  - lgamma((double)n + a + bpr) - norm;
        pf.v[PRIOR_LEN - 1 - k] = (float)exp(lp);
    }

    dca_kernel<<<dim3(BB), dim3(1024), 0, stream>>>(
        (const float*)d_in[0], (const float*)d_in[1], (const float*)d_in[2],
        (const float*)d_in[3], (const float*)d_in[4], (const float*)d_in[5],
        (const float*)d_in[6], (const float*)d_in[7], (const float*)d_in[8],
        (const float*)d_in[9], (float*)d_out, pf);
}